// Round 18
// baseline (236.846 us; speedup 1.0000x reference)
//
#include <hip/hip_runtime.h>
#include <math.h>

#define BB 4
#define NN 8192
#define MM 2048
#define CC 64
#define KNB 32
#define CIN 67   // 3 + CC
#define H1 64
#define H2 128
#define XP 36    // padded row stride for x^T / h1^T tile (float4-aligned)
#define AB 4     // anchors per mlp block
#define NCAP 3072

// ---------------- init: zero per-batch maxnorm cells ----------------
__global__ void init_kernel(int* maxnorm) {
    if (threadIdx.x < BB) maxnorm[threadIdx.x] = 0;
}

// ---------------- coord4 pack: (cx,cy,cz,c2) per point; c2 formula bit-identical ----------------
__global__ __launch_bounds__(256) void coord4_kernel(const float* __restrict__ coord,
                                                     float4* __restrict__ c4) {
    const int t = blockIdx.x * 256 + threadIdx.x;   // t in [0, BB*NN)
    if (t < BB * NN) {
        float cx = coord[t * 3 + 0], cy = coord[t * 3 + 1], cz = coord[t * 3 + 2];
        float c2 = __fadd_rn(__fadd_rn(__fmul_rn(cx, cx), __fmul_rn(cy, cy)), __fmul_rn(cz, cz));
        float4 q; q.x = cx; q.y = cy; q.z = cz; q.w = c2;
        c4[t] = q;
    }
}

// ---------------- kNN: register radix select + U-prefilter + cheap survivor compaction ----------------
// Selection math identical to validated r13/r15. NEW: survivors (keys <= U, ~900 of
// 8192) are compacted to LDS with ONE atomicAdd per thread + predicated compile-time
// -indexed stores; the 4 histogram passes scan the compacted list (~3.5 iters/thread)
// instead of 4x32 predicated kreg scans. Same key multiset => bit-exact T. Emission
// and tie-breaking unchanged (kreg). Overflow (P~1e-4/block) -> exact r13 fallback.
__global__ __launch_bounds__(256, 4) void knn_kernel(
    const float4* __restrict__ c4buf, const float* __restrict__ anchor_coord,
    int* __restrict__ idxbuf, int* __restrict__ maxnorm)
{
    __shared__ unsigned hist[4][256];     // per-wave histogram copies
    __shared__ unsigned ckey[NCAP];       // compacted survivor keys
    __shared__ unsigned wmax[4];
    __shared__ unsigned wtot[4];
    __shared__ unsigned bc[2];            // [0]=chosen bin, [1]=rank within bin
    __shared__ unsigned nsel;             // emission counter
    __shared__ unsigned ns;               // compaction counter
    __shared__ int      selcell;
    __shared__ int      sel_s[KNB];

    const int anchor = blockIdx.x;
    const int b  = anchor >> 11;          // / MM
    const int mi = anchor & (MM - 1);
    const int tid = threadIdx.x;
    const int w = tid >> 6, lane = tid & 63;

    const float ax = anchor_coord[(b * MM + mi) * 3 + 0];
    const float ay = anchor_coord[(b * MM + mi) * 3 + 1];
    const float az = anchor_coord[(b * MM + mi) * 3 + 2];
    const float a2 = __fadd_rn(__fadd_rn(__fmul_rn(ax, ax), __fmul_rn(ay, ay)), __fmul_rn(az, az));

    const float4* c4b = c4buf + (size_t)b * NN;

    // distances (reference formula, bit-identical) -> monotone keys in REGISTERS
    unsigned kreg[32];
    unsigned tmin = 0xFFFFFFFFu;
    #pragma unroll
    for (int j = 0; j < 32; j++) {
        const int i = tid + 256 * j;
        const float4 cq = c4b[i];         // one global_load_dwordx4
        float dt = __fadd_rn(__fadd_rn(__fmul_rn(ax, cq.x), __fmul_rn(ay, cq.y)), __fmul_rn(az, cq.z));
        float d2 = __fadd_rn(__fsub_rn(a2, __fmul_rn(2.0f, dt)), cq.w);
        unsigned ub = __float_as_uint(d2);
        ub ^= (unsigned)((int)ub >> 31) | 0x80000000u;   // monotone: u32 order == float order
        kreg[j] = ub;
        tmin = tmin < ub ? tmin : ub;
    }

    // U = max over 32 designated per-thread minima => T <= U (>=32 keys <= U)
    unsigned um = tmin;
    um = max(um, (unsigned)__shfl_xor((int)um, 1));
    um = max(um, (unsigned)__shfl_xor((int)um, 2));
    um = max(um, (unsigned)__shfl_xor((int)um, 4));
    if (lane == 0) wmax[w] = um;
    if (tid == 0) { nsel = 0; ns = 0; }
    __syncthreads();
    const unsigned U = max(max(wmax[0], wmax[1]), max(wmax[2], wmax[3]));

    // ---- cheap survivor compaction: bitmask + ONE atomic + predicated stores ----
    unsigned smask = 0;
    #pragma unroll
    for (int j = 0; j < 32; j++) {
        if (kreg[j] <= U) smask |= 1u << j;
    }
    unsigned pos = atomicAdd(&ns, (unsigned)__popc(smask));
    #pragma unroll
    for (int j = 0; j < 32; j++) {
        if ((smask >> j) & 1u) {
            if (pos < NCAP) ckey[pos] = kreg[j];
            pos++;
        }
    }
    __syncthreads();
    const unsigned nsv = ns;
    const bool usec = (nsv <= NCAP);      // block-uniform

    unsigned prefix = 0, pmask = 0;
    unsigned k = KNB;

    #pragma unroll
    for (int pass = 0; pass < 4; pass++) {
        const int sh = 24 - 8 * pass;
        unsigned* hf = &hist[0][0];
        hf[tid] = 0; hf[tid + 256] = 0; hf[tid + 512] = 0; hf[tid + 768] = 0;
        __syncthreads();
        if (usec) {
            for (unsigned t = tid; t < nsv; t += 256) {
                unsigned kk = ckey[t];
                if ((kk & pmask) == prefix) atomicAdd(&hist[w][(kk >> sh) & 0xFFu], 1u);
            }
        } else {
            #pragma unroll
            for (int j = 0; j < 32; j++) {
                unsigned kk = kreg[j];
                if (kk <= U && (kk & pmask) == prefix) atomicAdd(&hist[w][(kk >> sh) & 0xFFu], 1u);
            }
        }
        __syncthreads();
        const unsigned h = hist[0][tid] + hist[1][tid] + hist[2][tid] + hist[3][tid];
        unsigned v = h;
        #pragma unroll
        for (int d = 1; d < 64; d <<= 1) {
            unsigned t = __shfl_up(v, d);
            if (lane >= d) v += t;
        }
        if (lane == 63) wtot[w] = v;
        __syncthreads();
        unsigned off = 0;
        #pragma unroll
        for (int ww = 0; ww < 3; ww++) if (ww < w) off += wtot[ww];
        v += off;
        const unsigned excl = v - h;
        if (excl < k && k <= v) { bc[0] = (unsigned)tid; bc[1] = k - excl; }
        __syncthreads();
        prefix |= bc[0] << sh;
        pmask  |= 0xFFu << sh;
        k = bc[1];
    }
    const unsigned T = prefix;            // exact key of the 32nd-smallest element

    // emission: all keys < T, then lowest-index ties (validated r13 path)
    unsigned tiemask = 0;
    #pragma unroll
    for (int j = 0; j < 32; j++) {
        unsigned kk = kreg[j];
        if (kk < T) { unsigned p2 = atomicAdd(&nsel, 1u); sel_s[p2] = tid + 256 * j; }
        else if (kk == T) tiemask |= 1u << j;
    }
    __syncthreads();
    const unsigned n_lt = nsel;
    const unsigned needed = KNB - n_lt;
    int last = -1;
    for (unsigned r = 0; r < needed; r++) {
        if (tid == 0) selcell = 0x7fffffff;
        __syncthreads();
        unsigned m = tiemask;
        while (m) {
            int j = __ffs(m) - 1; m &= m - 1;
            int idx = tid + 256 * j;
            if (idx > last) atomicMin(&selcell, idx);
        }
        __syncthreads();
        last = selcell;
        if (tid == 0) sel_s[n_lt + r] = last;
        __syncthreads();
    }

    // write indices; per-batch max ||delta||
    float nrm = 0.0f;
    if (tid < KNB) {
        int j = sel_s[tid];
        idxbuf[anchor * KNB + tid] = j;
        const float4 cq = c4b[j];
        float dx = __fsub_rn(cq.x, ax);
        float dy = __fsub_rn(cq.y, ay);
        float dz = __fsub_rn(cq.z, az);
        nrm = sqrtf(dx * dx + dy * dy + dz * dz);
    }
    if (tid < 64) {
        #pragma unroll
        for (int off = 32; off; off >>= 1) nrm = fmaxf(nrm, __shfl_xor(nrm, off));
        if (tid == 0) atomicMax(&maxnorm[b], __float_as_int(nrm));
    }
}

// ---------------- fused gather + MLP + maxpool: FOUR anchors per block (validated round 13) ----------------
__global__ __launch_bounds__(256, 4) void mlp_kernel(
    const float* __restrict__ feat, const float* __restrict__ coord,
    const float* __restrict__ anchor_feat, const float* __restrict__ anchor_coord,
    const float* __restrict__ W1, const float* __restrict__ b1,
    const float* __restrict__ g1, const float* __restrict__ be1,
    const float* __restrict__ W2, const float* __restrict__ b2,
    const float* __restrict__ g2, const float* __restrict__ be2,
    const int* __restrict__ maxnorm, const int* __restrict__ idxbuf,
    float* __restrict__ out)
{
    __shared__ __align__(16) float xst[AB][CIN * XP];  // x^T per anchor; rows 0..63 reused as h1^T
    __shared__ int sel[AB][KNB];

    const int a0g = blockIdx.x * AB;      // first anchor of this block
    const int b   = a0g >> 11;            // all AB anchors share the batch
    const int tid = threadIdx.x;
    const int w = tid >> 6, lane = tid & 63;
    const int g = tid >> 5, c = tid & 31; // group (k-quad) and channel-thread

    if (tid < AB * KNB) sel[tid >> 5][tid & 31] = idxbuf[(size_t)a0g * KNB + tid];
    __syncthreads();

    const float mn = __int_as_float(maxnorm[b]);

    // ---- gather: wave w owns anchor w (coalesced: lane = feature channel) ----
    {
        const int mi = (a0g + w) & (MM - 1);
        const float af = anchor_feat[((size_t)b * MM + mi) * CC + lane];
        #pragma unroll 8
        for (int kk = 0; kk < KNB; kk++) {
            const int nj = sel[w][kk];
            xst[w][(3 + lane) * XP + kk] = feat[((size_t)b * NN + nj) * CC + lane] - af;
        }
    }
    for (int t = tid; t < AB * KNB * 3; t += 256) {
        const int a = t / 96, r = t % 96, k = r / 3, j = r % 3;
        const int mi = (a0g + a) & (MM - 1);
        const int nj = sel[a][k];
        float d = __fsub_rn(coord[((size_t)b * NN + nj) * 3 + j],
                            anchor_coord[((size_t)b * MM + mi) * 3 + j]);
        xst[a][j * XP + k] = __fdiv_rn(d, mn);
    }
    __syncthreads();

    // ---- stage 1: ch = 2c, 2c+1; k = 4g..4g+3 of each anchor ----
    const int ch1 = 2 * c;
    const float b1a = b1[ch1], b1b = b1[ch1 + 1];
    float accA[AB][4], accB[AB][4];
    #pragma unroll
    for (int a = 0; a < AB; a++)
        #pragma unroll
        for (int kk = 0; kk < 4; kk++) { accA[a][kk] = b1a; accB[a][kk] = b1b; }
    #pragma unroll 4
    for (int j = 0; j < CIN; j++) {
        const float2 wv = *(const float2*)&W1[j * H1 + ch1];
        #pragma unroll
        for (int a = 0; a < AB; a++) {
            const float4 xq = *(const float4*)&xst[a][j * XP + 4 * g];
            accA[a][0] = fmaf(xq.x, wv.x, accA[a][0]);  accB[a][0] = fmaf(xq.x, wv.y, accB[a][0]);
            accA[a][1] = fmaf(xq.y, wv.x, accA[a][1]);  accB[a][1] = fmaf(xq.y, wv.y, accB[a][1]);
            accA[a][2] = fmaf(xq.z, wv.x, accA[a][2]);  accB[a][2] = fmaf(xq.z, wv.y, accB[a][2]);
            accA[a][3] = fmaf(xq.w, wv.x, accA[a][3]);  accB[a][3] = fmaf(xq.w, wv.y, accB[a][3]);
        }
    }
    const float g1a = g1[ch1], g1b = g1[ch1 + 1];
    const float be1a = be1[ch1], be1b = be1[ch1 + 1];
    float y1A[AB][4], y1B[AB][4];
    #pragma unroll
    for (int a = 0; a < AB; a++) {
        #pragma unroll
        for (int kk = 0; kk < 4; kk++) {
            float s  = accA[a][kk] + accB[a][kk];
            float s2 = accA[a][kk] * accA[a][kk] + accB[a][kk] * accB[a][kk];
            #pragma unroll
            for (int off = 16; off; off >>= 1) { s += __shfl_xor(s, off); s2 += __shfl_xor(s2, off); }
            float mu  = s  * (1.0f / H1);
            float var = s2 * (1.0f / H1) - mu * mu;
            float r = rsqrtf(var + 1e-6f);
            y1A[a][kk] = fmaxf(fmaf((accA[a][kk] - mu) * r, g1a, be1a), 0.0f);
            y1B[a][kk] = fmaxf(fmaf((accB[a][kk] - mu) * r, g1b, be1b), 0.0f);
        }
    }
    __syncthreads();                 // all x reads complete before overlay
    #pragma unroll
    for (int a = 0; a < AB; a++)
        #pragma unroll
        for (int kk = 0; kk < 4; kk++) {
            xst[a][ch1 * XP + 4 * g + kk]       = y1A[a][kk];
            xst[a][(ch1 + 1) * XP + 4 * g + kk] = y1B[a][kk];
        }
    __syncthreads();

    // ---- stage 2: ch = 4c..4c+3; k = 4g..4g+3 of each anchor ----
    const int ch2 = 4 * c;
    const float4 b2v = *(const float4*)&b2[ch2];
    float a2c[AB][16];   // [anchor][ci*4+kk]
    #pragma unroll
    for (int a = 0; a < AB; a++)
        #pragma unroll
        for (int kk = 0; kk < 4; kk++) {
            a2c[a][0 * 4 + kk] = b2v.x; a2c[a][1 * 4 + kk] = b2v.y;
            a2c[a][2 * 4 + kk] = b2v.z; a2c[a][3 * 4 + kk] = b2v.w;
        }
    #pragma unroll 2
    for (int j = 0; j < H1; j++) {
        const float4 wv = *(const float4*)&W2[j * H2 + ch2];
        #pragma unroll
        for (int a = 0; a < AB; a++) {
            const float4 hq = *(const float4*)&xst[a][j * XP + 4 * g];
            a2c[a][0]  = fmaf(hq.x, wv.x, a2c[a][0]);  a2c[a][1]  = fmaf(hq.y, wv.x, a2c[a][1]);
            a2c[a][2]  = fmaf(hq.z, wv.x, a2c[a][2]);  a2c[a][3]  = fmaf(hq.w, wv.x, a2c[a][3]);
            a2c[a][4]  = fmaf(hq.x, wv.y, a2c[a][4]);  a2c[a][5]  = fmaf(hq.y, wv.y, a2c[a][5]);
            a2c[a][6]  = fmaf(hq.z, wv.y, a2c[a][6]);  a2c[a][7]  = fmaf(hq.w, wv.y, a2c[a][7]);
            a2c[a][8]  = fmaf(hq.x, wv.z, a2c[a][8]);  a2c[a][9]  = fmaf(hq.y, wv.z, a2c[a][9]);
            a2c[a][10] = fmaf(hq.z, wv.z, a2c[a][10]); a2c[a][11] = fmaf(hq.w, wv.z, a2c[a][11]);
            a2c[a][12] = fmaf(hq.x, wv.w, a2c[a][12]); a2c[a][13] = fmaf(hq.y, wv.w, a2c[a][13]);
            a2c[a][14] = fmaf(hq.z, wv.w, a2c[a][14]); a2c[a][15] = fmaf(hq.w, wv.w, a2c[a][15]);
        }
    }
    const float4 g2v  = *(const float4*)&g2[ch2];
    const float4 be2v = *(const float4*)&be2[ch2];
    float mx[AB][4];
    #pragma unroll
    for (int a = 0; a < AB; a++) {
        mx[a][0] = -INFINITY; mx[a][1] = -INFINITY; mx[a][2] = -INFINITY; mx[a][3] = -INFINITY;
        #pragma unroll
        for (int kk = 0; kk < 4; kk++) {
            float v0 = a2c[a][kk], v1 = a2c[a][4 + kk], v2 = a2c[a][8 + kk], v3 = a2c[a][12 + kk];
            float s  = (v0 + v1) + (v2 + v3);
            float s2 = (v0 * v0 + v1 * v1) + (v2 * v2 + v3 * v3);
            #pragma unroll
            for (int off = 16; off; off >>= 1) { s += __shfl_xor(s, off); s2 += __shfl_xor(s2, off); }
            float mu  = s  * (1.0f / H2);
            float var = s2 * (1.0f / H2) - mu * mu;
            float r = rsqrtf(var + 1e-6f);
            mx[a][0] = fmaxf(mx[a][0], fmaxf(fmaf((v0 - mu) * r, g2v.x, be2v.x), 0.0f));
            mx[a][1] = fmaxf(mx[a][1], fmaxf(fmaf((v1 - mu) * r, g2v.y, be2v.y), 0.0f));
            mx[a][2] = fmaxf(mx[a][2], fmaxf(fmaf((v2 - mu) * r, g2v.z, be2v.z), 0.0f));
            mx[a][3] = fmaxf(mx[a][3], fmaxf(fmaf((v3 - mu) * r, g2v.w, be2v.w), 0.0f));
        }
    }
    __syncthreads();                 // xst dead: alias as pmax[a][g][128]
    float* pmaxp = &xst[0][0];
    #pragma unroll
    for (int a = 0; a < AB; a++) {
        float4 q; q.x = mx[a][0]; q.y = mx[a][1]; q.z = mx[a][2]; q.w = mx[a][3];
        *(float4*)&pmaxp[(a * 8 + g) * H2 + ch2] = q;
    }
    __syncthreads();
    #pragma unroll
    for (int t = tid; t < AB * H2; t += 256) {
        const int a = t >> 7, ch = t & 127;
        float vv = pmaxp[(a * 8 + 0) * H2 + ch];
        #pragma unroll
        for (int gg = 1; gg < 8; gg++) vv = fmaxf(vv, pmaxp[(a * 8 + gg) * H2 + ch]);
        out[(size_t)(a0g + a) * H2 + ch] = vv;
    }
}

extern "C" void kernel_launch(void* const* d_in, const int* in_sizes, int n_in,
                              void* d_out, int out_size, void* d_ws, size_t ws_size,
                              hipStream_t stream) {
    const float* feat         = (const float*)d_in[0];
    const float* coord        = (const float*)d_in[1];
    const float* anchor_feat  = (const float*)d_in[2];
    const float* anchor_coord = (const float*)d_in[3];
    const float* W1  = (const float*)d_in[4];
    const float* b1  = (const float*)d_in[5];
    const float* g1  = (const float*)d_in[6];
    const float* be1 = (const float*)d_in[7];
    const float* W2  = (const float*)d_in[8];
    const float* b2  = (const float*)d_in[9];
    const float* g2  = (const float*)d_in[10];
    const float* be2 = (const float*)d_in[11];
    float* out = (float*)d_out;

    int*    maxn   = (int*)d_ws;                                  // 16 ints
    int*    idxbuf = (int*)d_ws + 16;                             // BB*MM*KNB ints
    float4* c4buf  = (float4*)((int*)d_ws + 16 + BB * MM * KNB);  // BB*NN float4 (16B aligned)

    init_kernel<<<1, 64, 0, stream>>>(maxn);
    coord4_kernel<<<(BB * NN + 255) / 256, 256, 0, stream>>>(coord, c4buf);
    knn_kernel<<<BB * MM, 256, 0, stream>>>(c4buf, anchor_coord, idxbuf, maxn);
    mlp_kernel<<<BB * MM / AB, 256, 0, stream>>>(feat, coord, anchor_feat, anchor_coord,
                                                 W1, b1, g1, be1, W2, b2, g2, be2,
                                                 maxn, idxbuf, out);
}

// Round 19
// 227.911 us; speedup vs baseline: 1.0392x; 1.0392x over previous
//
#include <hip/hip_runtime.h>
#include <math.h>

#define BB 4
#define NN 8192
#define MM 2048
#define CC 64
#define KNB 32
#define CIN 67   // 3 + CC
#define H1 64
#define H2 128
#define XP 36    // padded row stride for x^T / h1^T tile (float4-aligned)
#define AB 4     // anchors per mlp block

// ---------------- init: zero per-batch maxnorm cells ----------------
__global__ void init_kernel(int* maxnorm) {
    if (threadIdx.x < BB) maxnorm[threadIdx.x] = 0;
}

// ---------------- coord4 pack: (cx,cy,cz,c2) per point; c2 formula bit-identical ----------------
__global__ __launch_bounds__(256) void coord4_kernel(const float* __restrict__ coord,
                                                     float4* __restrict__ c4) {
    const int t = blockIdx.x * 256 + threadIdx.x;   // t in [0, BB*NN)
    if (t < BB * NN) {
        float cx = coord[t * 3 + 0], cy = coord[t * 3 + 1], cz = coord[t * 3 + 2];
        float c2 = __fadd_rn(__fadd_rn(__fmul_rn(cx, cx), __fmul_rn(cy, cy)), __fmul_rn(cz, cz));
        float4 q; q.x = cx; q.y = cy; q.z = cz; q.w = c2;
        c4[t] = q;
    }
}

// ---------------- kNN: register radix select + U-prefilter (validated round 15 body) ----------------
// NEW vs r15: __launch_bounds__(256, 6). r13/r15's (256,4) capped occupancy at 56%;
// r17's (256,8) forced VGPR 40->32 WITH SPILLS (WRITE_SIZE 29MB). (256,6) = 24
// waves/CU with a ~341-VGPR budget: occupancy up 1.5x, zero spill pressure.
__global__ __launch_bounds__(256, 6) void knn_kernel(
    const float4* __restrict__ c4buf, const float* __restrict__ anchor_coord,
    int* __restrict__ idxbuf, int* __restrict__ maxnorm)
{
    __shared__ unsigned hist[4][256];     // per-wave histogram copies
    __shared__ unsigned wmax[4];
    __shared__ unsigned wtot[4];
    __shared__ unsigned bc[2];            // [0]=chosen bin, [1]=rank within bin
    __shared__ unsigned nsel;
    __shared__ int      selcell;
    __shared__ int      sel_s[KNB];

    const int anchor = blockIdx.x;
    const int b  = anchor >> 11;          // / MM
    const int mi = anchor & (MM - 1);
    const int tid = threadIdx.x;
    const int w = tid >> 6, lane = tid & 63;

    const float ax = anchor_coord[(b * MM + mi) * 3 + 0];
    const float ay = anchor_coord[(b * MM + mi) * 3 + 1];
    const float az = anchor_coord[(b * MM + mi) * 3 + 2];
    const float a2 = __fadd_rn(__fadd_rn(__fmul_rn(ax, ax), __fmul_rn(ay, ay)), __fmul_rn(az, az));

    const float4* c4b = c4buf + (size_t)b * NN;

    // distances (reference formula, bit-identical) -> monotone keys in REGISTERS
    unsigned kreg[32];
    unsigned tmin = 0xFFFFFFFFu;
    #pragma unroll
    for (int j = 0; j < 32; j++) {
        const int i = tid + 256 * j;
        const float4 cq = c4b[i];         // one global_load_dwordx4
        float dt = __fadd_rn(__fadd_rn(__fmul_rn(ax, cq.x), __fmul_rn(ay, cq.y)), __fmul_rn(az, cq.z));
        float d2 = __fadd_rn(__fsub_rn(a2, __fmul_rn(2.0f, dt)), cq.w);
        unsigned ub = __float_as_uint(d2);
        ub ^= (unsigned)((int)ub >> 31) | 0x80000000u;   // monotone: u32 order == float order
        kreg[j] = ub;
        tmin = tmin < ub ? tmin : ub;
    }

    // U = max over 32 designated per-thread minima => T <= U (>=32 keys <= U)
    unsigned um = tmin;
    um = max(um, (unsigned)__shfl_xor((int)um, 1));
    um = max(um, (unsigned)__shfl_xor((int)um, 2));
    um = max(um, (unsigned)__shfl_xor((int)um, 4));
    if (lane == 0) wmax[w] = um;
    if (tid == 0) nsel = 0;
    __syncthreads();
    const unsigned U = max(max(wmax[0], wmax[1]), max(wmax[2], wmax[3]));

    unsigned prefix = 0, pmask = 0;
    unsigned k = KNB;

    #pragma unroll
    for (int pass = 0; pass < 4; pass++) {
        const int sh = 24 - 8 * pass;
        unsigned* hf = &hist[0][0];
        hf[tid] = 0; hf[tid + 256] = 0; hf[tid + 512] = 0; hf[tid + 768] = 0;
        __syncthreads();
        #pragma unroll
        for (int j = 0; j < 32; j++) {
            unsigned kk = kreg[j];
            if (kk <= U && (kk & pmask) == prefix) atomicAdd(&hist[w][(kk >> sh) & 0xFFu], 1u);
        }
        __syncthreads();
        const unsigned h = hist[0][tid] + hist[1][tid] + hist[2][tid] + hist[3][tid];
        unsigned v = h;
        #pragma unroll
        for (int d = 1; d < 64; d <<= 1) {
            unsigned t = __shfl_up(v, d);
            if (lane >= d) v += t;
        }
        if (lane == 63) wtot[w] = v;
        __syncthreads();
        unsigned off = 0;
        #pragma unroll
        for (int ww = 0; ww < 3; ww++) if (ww < w) off += wtot[ww];
        v += off;
        const unsigned excl = v - h;
        if (excl < k && k <= v) { bc[0] = (unsigned)tid; bc[1] = k - excl; }
        __syncthreads();
        prefix |= bc[0] << sh;
        pmask  |= 0xFFu << sh;
        k = bc[1];
    }
    const unsigned T = prefix;            // exact key of the 32nd-smallest element

    // emission: all keys < T, then lowest-index ties
    unsigned tiemask = 0;
    #pragma unroll
    for (int j = 0; j < 32; j++) {
        unsigned kk = kreg[j];
        if (kk < T) { unsigned pos = atomicAdd(&nsel, 1u); sel_s[pos] = tid + 256 * j; }
        else if (kk == T) tiemask |= 1u << j;
    }
    __syncthreads();
    const unsigned n_lt = nsel;
    const unsigned needed = KNB - n_lt;
    int last = -1;
    for (unsigned r = 0; r < needed; r++) {
        if (tid == 0) selcell = 0x7fffffff;
        __syncthreads();
        unsigned m = tiemask;
        while (m) {
            int j = __ffs(m) - 1; m &= m - 1;
            int idx = tid + 256 * j;
            if (idx > last) atomicMin(&selcell, idx);
        }
        __syncthreads();
        last = selcell;
        if (tid == 0) sel_s[n_lt + r] = last;
        __syncthreads();
    }

    // write indices; per-batch max ||delta||
    float nrm = 0.0f;
    if (tid < KNB) {
        int j = sel_s[tid];
        idxbuf[anchor * KNB + tid] = j;
        const float4 cq = c4b[j];
        float dx = __fsub_rn(cq.x, ax);
        float dy = __fsub_rn(cq.y, ay);
        float dz = __fsub_rn(cq.z, az);
        nrm = sqrtf(dx * dx + dy * dy + dz * dz);
    }
    if (tid < 64) {
        #pragma unroll
        for (int off = 32; off; off >>= 1) nrm = fmaxf(nrm, __shfl_xor(nrm, off));
        if (tid == 0) atomicMax(&maxnorm[b], __float_as_int(nrm));
    }
}

// ---------------- fused gather + MLP + maxpool: FOUR anchors per block (validated round 13) ----------------
__global__ __launch_bounds__(256, 4) void mlp_kernel(
    const float* __restrict__ feat, const float* __restrict__ coord,
    const float* __restrict__ anchor_feat, const float* __restrict__ anchor_coord,
    const float* __restrict__ W1, const float* __restrict__ b1,
    const float* __restrict__ g1, const float* __restrict__ be1,
    const float* __restrict__ W2, const float* __restrict__ b2,
    const float* __restrict__ g2, const float* __restrict__ be2,
    const int* __restrict__ maxnorm, const int* __restrict__ idxbuf,
    float* __restrict__ out)
{
    __shared__ __align__(16) float xst[AB][CIN * XP];  // x^T per anchor; rows 0..63 reused as h1^T
    __shared__ int sel[AB][KNB];

    const int a0g = blockIdx.x * AB;      // first anchor of this block
    const int b   = a0g >> 11;            // all AB anchors share the batch
    const int tid = threadIdx.x;
    const int w = tid >> 6, lane = tid & 63;
    const int g = tid >> 5, c = tid & 31; // group (k-quad) and channel-thread

    if (tid < AB * KNB) sel[tid >> 5][tid & 31] = idxbuf[(size_t)a0g * KNB + tid];
    __syncthreads();

    const float mn = __int_as_float(maxnorm[b]);

    // ---- gather: wave w owns anchor w (coalesced: lane = feature channel) ----
    {
        const int mi = (a0g + w) & (MM - 1);
        const float af = anchor_feat[((size_t)b * MM + mi) * CC + lane];
        #pragma unroll 8
        for (int kk = 0; kk < KNB; kk++) {
            const int nj = sel[w][kk];
            xst[w][(3 + lane) * XP + kk] = feat[((size_t)b * NN + nj) * CC + lane] - af;
        }
    }
    for (int t = tid; t < AB * KNB * 3; t += 256) {
        const int a = t / 96, r = t % 96, k = r / 3, j = r % 3;
        const int mi = (a0g + a) & (MM - 1);
        const int nj = sel[a][k];
        float d = __fsub_rn(coord[((size_t)b * NN + nj) * 3 + j],
                            anchor_coord[((size_t)b * MM + mi) * 3 + j]);
        xst[a][j * XP + k] = __fdiv_rn(d, mn);
    }
    __syncthreads();

    // ---- stage 1: ch = 2c, 2c+1; k = 4g..4g+3 of each anchor ----
    const int ch1 = 2 * c;
    const float b1a = b1[ch1], b1b = b1[ch1 + 1];
    float accA[AB][4], accB[AB][4];
    #pragma unroll
    for (int a = 0; a < AB; a++)
        #pragma unroll
        for (int kk = 0; kk < 4; kk++) { accA[a][kk] = b1a; accB[a][kk] = b1b; }
    #pragma unroll 4
    for (int j = 0; j < CIN; j++) {
        const float2 wv = *(const float2*)&W1[j * H1 + ch1];
        #pragma unroll
        for (int a = 0; a < AB; a++) {
            const float4 xq = *(const float4*)&xst[a][j * XP + 4 * g];
            accA[a][0] = fmaf(xq.x, wv.x, accA[a][0]);  accB[a][0] = fmaf(xq.x, wv.y, accB[a][0]);
            accA[a][1] = fmaf(xq.y, wv.x, accA[a][1]);  accB[a][1] = fmaf(xq.y, wv.y, accB[a][1]);
            accA[a][2] = fmaf(xq.z, wv.x, accA[a][2]);  accB[a][2] = fmaf(xq.z, wv.y, accB[a][2]);
            accA[a][3] = fmaf(xq.w, wv.x, accA[a][3]);  accB[a][3] = fmaf(xq.w, wv.y, accB[a][3]);
        }
    }
    const float g1a = g1[ch1], g1b = g1[ch1 + 1];
    const float be1a = be1[ch1], be1b = be1[ch1 + 1];
    float y1A[AB][4], y1B[AB][4];
    #pragma unroll
    for (int a = 0; a < AB; a++) {
        #pragma unroll
        for (int kk = 0; kk < 4; kk++) {
            float s  = accA[a][kk] + accB[a][kk];
            float s2 = accA[a][kk] * accA[a][kk] + accB[a][kk] * accB[a][kk];
            #pragma unroll
            for (int off = 16; off; off >>= 1) { s += __shfl_xor(s, off); s2 += __shfl_xor(s2, off); }
            float mu  = s  * (1.0f / H1);
            float var = s2 * (1.0f / H1) - mu * mu;
            float r = rsqrtf(var + 1e-6f);
            y1A[a][kk] = fmaxf(fmaf((accA[a][kk] - mu) * r, g1a, be1a), 0.0f);
            y1B[a][kk] = fmaxf(fmaf((accB[a][kk] - mu) * r, g1b, be1b), 0.0f);
        }
    }
    __syncthreads();                 // all x reads complete before overlay
    #pragma unroll
    for (int a = 0; a < AB; a++)
        #pragma unroll
        for (int kk = 0; kk < 4; kk++) {
            xst[a][ch1 * XP + 4 * g + kk]       = y1A[a][kk];
            xst[a][(ch1 + 1) * XP + 4 * g + kk] = y1B[a][kk];
        }
    __syncthreads();

    // ---- stage 2: ch = 4c..4c+3; k = 4g..4g+3 of each anchor ----
    const int ch2 = 4 * c;
    const float4 b2v = *(const float4*)&b2[ch2];
    float a2c[AB][16];   // [anchor][ci*4+kk]
    #pragma unroll
    for (int a = 0; a < AB; a++)
        #pragma unroll
        for (int kk = 0; kk < 4; kk++) {
            a2c[a][0 * 4 + kk] = b2v.x; a2c[a][1 * 4 + kk] = b2v.y;
            a2c[a][2 * 4 + kk] = b2v.z; a2c[a][3 * 4 + kk] = b2v.w;
        }
    #pragma unroll 2
    for (int j = 0; j < H1; j++) {
        const float4 wv = *(const float4*)&W2[j * H2 + ch2];
        #pragma unroll
        for (int a = 0; a < AB; a++) {
            const float4 hq = *(const float4*)&xst[a][j * XP + 4 * g];
            a2c[a][0]  = fmaf(hq.x, wv.x, a2c[a][0]);  a2c[a][1]  = fmaf(hq.y, wv.x, a2c[a][1]);
            a2c[a][2]  = fmaf(hq.z, wv.x, a2c[a][2]);  a2c[a][3]  = fmaf(hq.w, wv.x, a2c[a][3]);
            a2c[a][4]  = fmaf(hq.x, wv.y, a2c[a][4]);  a2c[a][5]  = fmaf(hq.y, wv.y, a2c[a][5]);
            a2c[a][6]  = fmaf(hq.z, wv.y, a2c[a][6]);  a2c[a][7]  = fmaf(hq.w, wv.y, a2c[a][7]);
            a2c[a][8]  = fmaf(hq.x, wv.z, a2c[a][8]);  a2c[a][9]  = fmaf(hq.y, wv.z, a2c[a][9]);
            a2c[a][10] = fmaf(hq.z, wv.z, a2c[a][10]); a2c[a][11] = fmaf(hq.w, wv.z, a2c[a][11]);
            a2c[a][12] = fmaf(hq.x, wv.w, a2c[a][12]); a2c[a][13] = fmaf(hq.y, wv.w, a2c[a][13]);
            a2c[a][14] = fmaf(hq.z, wv.w, a2c[a][14]); a2c[a][15] = fmaf(hq.w, wv.w, a2c[a][15]);
        }
    }
    const float4 g2v  = *(const float4*)&g2[ch2];
    const float4 be2v = *(const float4*)&be2[ch2];
    float mx[AB][4];
    #pragma unroll
    for (int a = 0; a < AB; a++) {
        mx[a][0] = -INFINITY; mx[a][1] = -INFINITY; mx[a][2] = -INFINITY; mx[a][3] = -INFINITY;
        #pragma unroll
        for (int kk = 0; kk < 4; kk++) {
            float v0 = a2c[a][kk], v1 = a2c[a][4 + kk], v2 = a2c[a][8 + kk], v3 = a2c[a][12 + kk];
            float s  = (v0 + v1) + (v2 + v3);
            float s2 = (v0 * v0 + v1 * v1) + (v2 * v2 + v3 * v3);
            #pragma unroll
            for (int off = 16; off; off >>= 1) { s += __shfl_xor(s, off); s2 += __shfl_xor(s2, off); }
            float mu  = s  * (1.0f / H2);
            float var = s2 * (1.0f / H2) - mu * mu;
            float r = rsqrtf(var + 1e-6f);
            mx[a][0] = fmaxf(mx[a][0], fmaxf(fmaf((v0 - mu) * r, g2v.x, be2v.x), 0.0f));
            mx[a][1] = fmaxf(mx[a][1], fmaxf(fmaf((v1 - mu) * r, g2v.y, be2v.y), 0.0f));
            mx[a][2] = fmaxf(mx[a][2], fmaxf(fmaf((v2 - mu) * r, g2v.z, be2v.z), 0.0f));
            mx[a][3] = fmaxf(mx[a][3], fmaxf(fmaf((v3 - mu) * r, g2v.w, be2v.w), 0.0f));
        }
    }
    __syncthreads();                 // xst dead: alias as pmax[a][g][128]
    float* pmaxp = &xst[0][0];
    #pragma unroll
    for (int a = 0; a < AB; a++) {
        float4 q; q.x = mx[a][0]; q.y = mx[a][1]; q.z = mx[a][2]; q.w = mx[a][3];
        *(float4*)&pmaxp[(a * 8 + g) * H2 + ch2] = q;
    }
    __syncthreads();
    #pragma unroll
    for (int t = tid; t < AB * H2; t += 256) {
        const int a = t >> 7, ch = t & 127;
        float vv = pmaxp[(a * 8 + 0) * H2 + ch];
        #pragma unroll
        for (int gg = 1; gg < 8; gg++) vv = fmaxf(vv, pmaxp[(a * 8 + gg) * H2 + ch]);
        out[(size_t)(a0g + a) * H2 + ch] = vv;
    }
}

extern "C" void kernel_launch(void* const* d_in, const int* in_sizes, int n_in,
                              void* d_out, int out_size, void* d_ws, size_t ws_size,
                              hipStream_t stream) {
    const float* feat         = (const float*)d_in[0];
    const float* coord        = (const float*)d_in[1];
    const float* anchor_feat  = (const float*)d_in[2];
    const float* anchor_coord = (const float*)d_in[3];
    const float* W1  = (const float*)d_in[4];
    const float* b1  = (const float*)d_in[5];
    const float* g1  = (const float*)d_in[6];
    const float* be1 = (const float*)d_in[7];
    const float* W2  = (const float*)d_in[8];
    const float* b2  = (const float*)d_in[9];
    const float* g2  = (const float*)d_in[10];
    const float* be2 = (const float*)d_in[11];
    float* out = (float*)d_out;

    int*    maxn   = (int*)d_ws;                                  // 16 ints
    int*    idxbuf = (int*)d_ws + 16;                             // BB*MM*KNB ints
    float4* c4buf  = (float4*)((int*)d_ws + 16 + BB * MM * KNB);  // BB*NN float4 (16B aligned)

    init_kernel<<<1, 64, 0, stream>>>(maxn);
    coord4_kernel<<<(BB * NN + 255) / 256, 256, 0, stream>>>(coord, c4buf);
    knn_kernel<<<BB * MM, 256, 0, stream>>>(c4buf, anchor_coord, idxbuf, maxn);
    mlp_kernel<<<BB * MM / AB, 256, 0, stream>>>(feat, coord, anchor_feat, anchor_coord,
                                                 W1, b1, g1, be1, W2, b2, g2, be2,
                                                 maxn, idxbuf, out);
}

// Round 20
// 204.655 us; speedup vs baseline: 1.1573x; 1.1136x over previous
//
#include <hip/hip_runtime.h>
#include <math.h>

#define BB 4
#define NN 8192
#define MM 2048
#define CC 64
#define KNB 32
#define CIN 67   // 3 + CC
#define H1 64
#define H2 128
#define XP 36    // padded row stride for x^T / h1^T tile (float4-aligned)
#define AB 4     // anchors per mlp block

// ---------------- init: zero per-batch maxnorm cells ----------------
__global__ void init_kernel(int* maxnorm) {
    if (threadIdx.x < BB) maxnorm[threadIdx.x] = 0;
}

// ---------------- coord4 pack: (cx,cy,cz,c2) per point; c2 formula bit-identical ----------------
__global__ __launch_bounds__(256) void coord4_kernel(const float* __restrict__ coord,
                                                     float4* __restrict__ c4) {
    const int t = blockIdx.x * 256 + threadIdx.x;   // t in [0, BB*NN)
    if (t < BB * NN) {
        float cx = coord[t * 3 + 0], cy = coord[t * 3 + 1], cz = coord[t * 3 + 2];
        float c2 = __fadd_rn(__fadd_rn(__fmul_rn(cx, cx), __fmul_rn(cy, cy)), __fmul_rn(cz, cz));
        float4 q; q.x = cx; q.y = cy; q.z = cz; q.w = c2;
        c4[t] = q;
    }
}

// ---------------- kNN: TWO anchors per block; register radix select + U-prefilter ----------------
// Per-anchor selection math byte-identical to validated r13/r15. Point loads,
// addressing, barriers, hist-zeroing amortized over 2 anchors (r13's mlp trick).
// U-check dropped in passes 1-3 (provably redundant: == r7's validated no-filter
// multiset for the established prefix). Both anchors share one batch (a0 even).
__global__ __launch_bounds__(256, 4) void knn_kernel(
    const float4* __restrict__ c4buf, const float* __restrict__ anchor_coord,
    int* __restrict__ idxbuf, int* __restrict__ maxnorm)
{
    __shared__ unsigned hist[2][4][256];  // [anchor][wave][bin]
    __shared__ unsigned wmax[2][4];
    __shared__ unsigned wtot[2][4];
    __shared__ unsigned bc[2][2];         // [anchor][0]=bin, [anchor][1]=rank
    __shared__ unsigned nsel[2];
    __shared__ int      selcell[2];
    __shared__ int      sel_s[2][KNB];

    const int a0 = blockIdx.x * 2;        // even: both anchors in same batch
    const int b  = a0 >> 11;              // / MM
    const int mi = a0 & (MM - 1);
    const int tid = threadIdx.x;
    const int w = tid >> 6, lane = tid & 63;

    const float axA = anchor_coord[(b * MM + mi) * 3 + 0];
    const float ayA = anchor_coord[(b * MM + mi) * 3 + 1];
    const float azA = anchor_coord[(b * MM + mi) * 3 + 2];
    const float a2A = __fadd_rn(__fadd_rn(__fmul_rn(axA, axA), __fmul_rn(ayA, ayA)), __fmul_rn(azA, azA));
    const float axB = anchor_coord[(b * MM + mi + 1) * 3 + 0];
    const float ayB = anchor_coord[(b * MM + mi + 1) * 3 + 1];
    const float azB = anchor_coord[(b * MM + mi + 1) * 3 + 2];
    const float a2B = __fadd_rn(__fadd_rn(__fmul_rn(axB, axB), __fmul_rn(ayB, ayB)), __fmul_rn(azB, azB));

    const float4* c4b = c4buf + (size_t)b * NN;

    // distances for BOTH anchors per point load (per-anchor formula bit-identical)
    unsigned kregA[32], kregB[32];
    unsigned tminA = 0xFFFFFFFFu, tminB = 0xFFFFFFFFu;
    #pragma unroll
    for (int j = 0; j < 32; j++) {
        const int i = tid + 256 * j;
        const float4 cq = c4b[i];         // ONE load feeds two anchors
        float dtA = __fadd_rn(__fadd_rn(__fmul_rn(axA, cq.x), __fmul_rn(ayA, cq.y)), __fmul_rn(azA, cq.z));
        float d2A = __fadd_rn(__fsub_rn(a2A, __fmul_rn(2.0f, dtA)), cq.w);
        unsigned ubA = __float_as_uint(d2A);
        ubA ^= (unsigned)((int)ubA >> 31) | 0x80000000u;
        kregA[j] = ubA;
        tminA = tminA < ubA ? tminA : ubA;
        float dtB = __fadd_rn(__fadd_rn(__fmul_rn(axB, cq.x), __fmul_rn(ayB, cq.y)), __fmul_rn(azB, cq.z));
        float d2B = __fadd_rn(__fsub_rn(a2B, __fmul_rn(2.0f, dtB)), cq.w);
        unsigned ubB = __float_as_uint(d2B);
        ubB ^= (unsigned)((int)ubB >> 31) | 0x80000000u;
        kregB[j] = ubB;
        tminB = tminB < ubB ? tminB : ubB;
    }

    // U per anchor (max of 32 designated per-thread minima => T <= U)
    unsigned umA = tminA, umB = tminB;
    umA = max(umA, (unsigned)__shfl_xor((int)umA, 1));
    umA = max(umA, (unsigned)__shfl_xor((int)umA, 2));
    umA = max(umA, (unsigned)__shfl_xor((int)umA, 4));
    umB = max(umB, (unsigned)__shfl_xor((int)umB, 1));
    umB = max(umB, (unsigned)__shfl_xor((int)umB, 2));
    umB = max(umB, (unsigned)__shfl_xor((int)umB, 4));
    if (lane == 0) { wmax[0][w] = umA; wmax[1][w] = umB; }
    if (tid == 0) { nsel[0] = 0; nsel[1] = 0; }
    __syncthreads();
    const unsigned UA = max(max(wmax[0][0], wmax[0][1]), max(wmax[0][2], wmax[0][3]));
    const unsigned UB = max(max(wmax[1][0], wmax[1][1]), max(wmax[1][2], wmax[1][3]));

    unsigned prefA = 0, prefB = 0, pmask = 0;
    unsigned kA = KNB, kB = KNB;

    #pragma unroll
    for (int pass = 0; pass < 4; pass++) {
        const int sh = 24 - 8 * pass;
        unsigned* hf = &hist[0][0][0];    // 2048 entries
        #pragma unroll
        for (int q = 0; q < 8; q++) hf[tid + 256 * q] = 0;
        __syncthreads();
        if (pass == 0) {
            #pragma unroll
            for (int j = 0; j < 32; j++) {
                if (kregA[j] <= UA) atomicAdd(&hist[0][w][kregA[j] >> 24], 1u);
                if (kregB[j] <= UB) atomicAdd(&hist[1][w][kregB[j] >> 24], 1u);
            }
        } else {
            #pragma unroll
            for (int j = 0; j < 32; j++) {
                // U-check redundant for pass>=1 (== r7's exact no-filter multiset)
                if ((kregA[j] & pmask) == prefA) atomicAdd(&hist[0][w][(kregA[j] >> sh) & 0xFFu], 1u);
                if ((kregB[j] & pmask) == prefB) atomicAdd(&hist[1][w][(kregB[j] >> sh) & 0xFFu], 1u);
            }
        }
        __syncthreads();
        const unsigned hA = hist[0][0][tid] + hist[0][1][tid] + hist[0][2][tid] + hist[0][3][tid];
        const unsigned hB = hist[1][0][tid] + hist[1][1][tid] + hist[1][2][tid] + hist[1][3][tid];
        unsigned vA = hA, vB = hB;
        #pragma unroll
        for (int d = 1; d < 64; d <<= 1) {
            unsigned tA = __shfl_up(vA, d);
            unsigned tB = __shfl_up(vB, d);
            if (lane >= d) { vA += tA; vB += tB; }
        }
        if (lane == 63) { wtot[0][w] = vA; wtot[1][w] = vB; }
        __syncthreads();
        unsigned offA = 0, offB = 0;
        #pragma unroll
        for (int ww = 0; ww < 3; ww++) if (ww < w) { offA += wtot[0][ww]; offB += wtot[1][ww]; }
        vA += offA; vB += offB;
        const unsigned exclA = vA - hA, exclB = vB - hB;
        if (exclA < kA && kA <= vA) { bc[0][0] = (unsigned)tid; bc[0][1] = kA - exclA; }
        if (exclB < kB && kB <= vB) { bc[1][0] = (unsigned)tid; bc[1][1] = kB - exclB; }
        __syncthreads();
        prefA |= bc[0][0] << sh; kA = bc[0][1];
        prefB |= bc[1][0] << sh; kB = bc[1][1];
        pmask |= 0xFFu << sh;
    }
    const unsigned TA = prefA, TB = prefB;

    // emission: all keys < T (set order irrelevant downstream)
    unsigned tiemaskA = 0, tiemaskB = 0;
    #pragma unroll
    for (int j = 0; j < 32; j++) {
        unsigned kkA = kregA[j];
        if (kkA < TA) { unsigned p = atomicAdd(&nsel[0], 1u); sel_s[0][p] = tid + 256 * j; }
        else if (kkA == TA) tiemaskA |= 1u << j;
        unsigned kkB = kregB[j];
        if (kkB < TB) { unsigned p = atomicAdd(&nsel[1], 1u); sel_s[1][p] = tid + 256 * j; }
        else if (kkB == TB) tiemaskB |= 1u << j;
    }
    __syncthreads();
    // ties, anchor A (>=1 round since n_lt < KNB)
    {
        const unsigned n_lt = nsel[0];
        const unsigned needed = KNB - n_lt;
        int last = -1;
        for (unsigned r = 0; r < needed; r++) {
            if (tid == 0) selcell[0] = 0x7fffffff;
            __syncthreads();
            unsigned m = tiemaskA;
            while (m) {
                int j = __ffs(m) - 1; m &= m - 1;
                int idx = tid + 256 * j;
                if (idx > last) atomicMin(&selcell[0], idx);
            }
            __syncthreads();
            last = selcell[0];
            if (tid == 0) sel_s[0][n_lt + r] = last;
            __syncthreads();
        }
    }
    // ties, anchor B
    {
        const unsigned n_lt = nsel[1];
        const unsigned needed = KNB - n_lt;
        int last = -1;
        for (unsigned r = 0; r < needed; r++) {
            if (tid == 0) selcell[1] = 0x7fffffff;
            __syncthreads();
            unsigned m = tiemaskB;
            while (m) {
                int j = __ffs(m) - 1; m &= m - 1;
                int idx = tid + 256 * j;
                if (idx > last) atomicMin(&selcell[1], idx);
            }
            __syncthreads();
            last = selcell[1];
            if (tid == 0) sel_s[1][n_lt + r] = last;
            __syncthreads();
        }
    }

    // write indices for both anchors; per-batch max ||delta|| (one combined reduce)
    float nrm = 0.0f;
    if (tid < 64) {
        const int a = tid >> 5;           // 0: anchor A, 1: anchor B
        const int s = tid & 31;
        const int j = sel_s[a][s];
        idxbuf[(size_t)(a0 + a) * KNB + s] = j;
        const float4 cq = c4b[j];
        const float ax = a ? axB : axA, ay = a ? ayB : ayA, az = a ? azB : azA;
        float dx = __fsub_rn(cq.x, ax);
        float dy = __fsub_rn(cq.y, ay);
        float dz = __fsub_rn(cq.z, az);
        nrm = sqrtf(dx * dx + dy * dy + dz * dz);
    }
    if (tid < 64) {
        #pragma unroll
        for (int off = 32; off; off >>= 1) nrm = fmaxf(nrm, __shfl_xor(nrm, off));
        if (tid == 0) atomicMax(&maxnorm[b], __float_as_int(nrm));
    }
}

// ---------------- fused gather + MLP + maxpool: FOUR anchors per block (validated round 13) ----------------
__global__ __launch_bounds__(256, 4) void mlp_kernel(
    const float* __restrict__ feat, const float* __restrict__ coord,
    const float* __restrict__ anchor_feat, const float* __restrict__ anchor_coord,
    const float* __restrict__ W1, const float* __restrict__ b1,
    const float* __restrict__ g1, const float* __restrict__ be1,
    const float* __restrict__ W2, const float* __restrict__ b2,
    const float* __restrict__ g2, const float* __restrict__ be2,
    const int* __restrict__ maxnorm, const int* __restrict__ idxbuf,
    float* __restrict__ out)
{
    __shared__ __align__(16) float xst[AB][CIN * XP];  // x^T per anchor; rows 0..63 reused as h1^T
    __shared__ int sel[AB][KNB];

    const int a0g = blockIdx.x * AB;      // first anchor of this block
    const int b   = a0g >> 11;            // all AB anchors share the batch
    const int tid = threadIdx.x;
    const int w = tid >> 6, lane = tid & 63;
    const int g = tid >> 5, c = tid & 31; // group (k-quad) and channel-thread

    if (tid < AB * KNB) sel[tid >> 5][tid & 31] = idxbuf[(size_t)a0g * KNB + tid];
    __syncthreads();

    const float mn = __int_as_float(maxnorm[b]);

    // ---- gather: wave w owns anchor w (coalesced: lane = feature channel) ----
    {
        const int mi = (a0g + w) & (MM - 1);
        const float af = anchor_feat[((size_t)b * MM + mi) * CC + lane];
        #pragma unroll 8
        for (int kk = 0; kk < KNB; kk++) {
            const int nj = sel[w][kk];
            xst[w][(3 + lane) * XP + kk] = feat[((size_t)b * NN + nj) * CC + lane] - af;
        }
    }
    for (int t = tid; t < AB * KNB * 3; t += 256) {
        const int a = t / 96, r = t % 96, k = r / 3, j = r % 3;
        const int mi = (a0g + a) & (MM - 1);
        const int nj = sel[a][k];
        float d = __fsub_rn(coord[((size_t)b * NN + nj) * 3 + j],
                            anchor_coord[((size_t)b * MM + mi) * 3 + j]);
        xst[a][j * XP + k] = __fdiv_rn(d, mn);
    }
    __syncthreads();

    // ---- stage 1: ch = 2c, 2c+1; k = 4g..4g+3 of each anchor ----
    const int ch1 = 2 * c;
    const float b1a = b1[ch1], b1b = b1[ch1 + 1];
    float accA[AB][4], accB[AB][4];
    #pragma unroll
    for (int a = 0; a < AB; a++)
        #pragma unroll
        for (int kk = 0; kk < 4; kk++) { accA[a][kk] = b1a; accB[a][kk] = b1b; }
    #pragma unroll 4
    for (int j = 0; j < CIN; j++) {
        const float2 wv = *(const float2*)&W1[j * H1 + ch1];
        #pragma unroll
        for (int a = 0; a < AB; a++) {
            const float4 xq = *(const float4*)&xst[a][j * XP + 4 * g];
            accA[a][0] = fmaf(xq.x, wv.x, accA[a][0]);  accB[a][0] = fmaf(xq.x, wv.y, accB[a][0]);
            accA[a][1] = fmaf(xq.y, wv.x, accA[a][1]);  accB[a][1] = fmaf(xq.y, wv.y, accB[a][1]);
            accA[a][2] = fmaf(xq.z, wv.x, accA[a][2]);  accB[a][2] = fmaf(xq.z, wv.y, accB[a][2]);
            accA[a][3] = fmaf(xq.w, wv.x, accA[a][3]);  accB[a][3] = fmaf(xq.w, wv.y, accB[a][3]);
        }
    }
    const float g1a = g1[ch1], g1b = g1[ch1 + 1];
    const float be1a = be1[ch1], be1b = be1[ch1 + 1];
    float y1A[AB][4], y1B[AB][4];
    #pragma unroll
    for (int a = 0; a < AB; a++) {
        #pragma unroll
        for (int kk = 0; kk < 4; kk++) {
            float s  = accA[a][kk] + accB[a][kk];
            float s2 = accA[a][kk] * accA[a][kk] + accB[a][kk] * accB[a][kk];
            #pragma unroll
            for (int off = 16; off; off >>= 1) { s += __shfl_xor(s, off); s2 += __shfl_xor(s2, off); }
            float mu  = s  * (1.0f / H1);
            float var = s2 * (1.0f / H1) - mu * mu;
            float r = rsqrtf(var + 1e-6f);
            y1A[a][kk] = fmaxf(fmaf((accA[a][kk] - mu) * r, g1a, be1a), 0.0f);
            y1B[a][kk] = fmaxf(fmaf((accB[a][kk] - mu) * r, g1b, be1b), 0.0f);
        }
    }
    __syncthreads();                 // all x reads complete before overlay
    #pragma unroll
    for (int a = 0; a < AB; a++)
        #pragma unroll
        for (int kk = 0; kk < 4; kk++) {
            xst[a][ch1 * XP + 4 * g + kk]       = y1A[a][kk];
            xst[a][(ch1 + 1) * XP + 4 * g + kk] = y1B[a][kk];
        }
    __syncthreads();

    // ---- stage 2: ch = 4c..4c+3; k = 4g..4g+3 of each anchor ----
    const int ch2 = 4 * c;
    const float4 b2v = *(const float4*)&b2[ch2];
    float a2c[AB][16];   // [anchor][ci*4+kk]
    #pragma unroll
    for (int a = 0; a < AB; a++)
        #pragma unroll
        for (int kk = 0; kk < 4; kk++) {
            a2c[a][0 * 4 + kk] = b2v.x; a2c[a][1 * 4 + kk] = b2v.y;
            a2c[a][2 * 4 + kk] = b2v.z; a2c[a][3 * 4 + kk] = b2v.w;
        }
    #pragma unroll 2
    for (int j = 0; j < H1; j++) {
        const float4 wv = *(const float4*)&W2[j * H2 + ch2];
        #pragma unroll
        for (int a = 0; a < AB; a++) {
            const float4 hq = *(const float4*)&xst[a][j * XP + 4 * g];
            a2c[a][0]  = fmaf(hq.x, wv.x, a2c[a][0]);  a2c[a][1]  = fmaf(hq.y, wv.x, a2c[a][1]);
            a2c[a][2]  = fmaf(hq.z, wv.x, a2c[a][2]);  a2c[a][3]  = fmaf(hq.w, wv.x, a2c[a][3]);
            a2c[a][4]  = fmaf(hq.x, wv.y, a2c[a][4]);  a2c[a][5]  = fmaf(hq.y, wv.y, a2c[a][5]);
            a2c[a][6]  = fmaf(hq.z, wv.y, a2c[a][6]);  a2c[a][7]  = fmaf(hq.w, wv.y, a2c[a][7]);
            a2c[a][8]  = fmaf(hq.x, wv.z, a2c[a][8]);  a2c[a][9]  = fmaf(hq.y, wv.z, a2c[a][9]);
            a2c[a][10] = fmaf(hq.z, wv.z, a2c[a][10]); a2c[a][11] = fmaf(hq.w, wv.z, a2c[a][11]);
            a2c[a][12] = fmaf(hq.x, wv.w, a2c[a][12]); a2c[a][13] = fmaf(hq.y, wv.w, a2c[a][13]);
            a2c[a][14] = fmaf(hq.z, wv.w, a2c[a][14]); a2c[a][15] = fmaf(hq.w, wv.w, a2c[a][15]);
        }
    }
    const float4 g2v  = *(const float4*)&g2[ch2];
    const float4 be2v = *(const float4*)&be2[ch2];
    float mx[AB][4];
    #pragma unroll
    for (int a = 0; a < AB; a++) {
        mx[a][0] = -INFINITY; mx[a][1] = -INFINITY; mx[a][2] = -INFINITY; mx[a][3] = -INFINITY;
        #pragma unroll
        for (int kk = 0; kk < 4; kk++) {
            float v0 = a2c[a][kk], v1 = a2c[a][4 + kk], v2 = a2c[a][8 + kk], v3 = a2c[a][12 + kk];
            float s  = (v0 + v1) + (v2 + v3);
            float s2 = (v0 * v0 + v1 * v1) + (v2 * v2 + v3 * v3);
            #pragma unroll
            for (int off = 16; off; off >>= 1) { s += __shfl_xor(s, off); s2 += __shfl_xor(s2, off); }
            float mu  = s  * (1.0f / H2);
            float var = s2 * (1.0f / H2) - mu * mu;
            float r = rsqrtf(var + 1e-6f);
            mx[a][0] = fmaxf(mx[a][0], fmaxf(fmaf((v0 - mu) * r, g2v.x, be2v.x), 0.0f));
            mx[a][1] = fmaxf(mx[a][1], fmaxf(fmaf((v1 - mu) * r, g2v.y, be2v.y), 0.0f));
            mx[a][2] = fmaxf(mx[a][2], fmaxf(fmaf((v2 - mu) * r, g2v.z, be2v.z), 0.0f));
            mx[a][3] = fmaxf(mx[a][3], fmaxf(fmaf((v3 - mu) * r, g2v.w, be2v.w), 0.0f));
        }
    }
    __syncthreads();                 // xst dead: alias as pmax[a][g][128]
    float* pmaxp = &xst[0][0];
    #pragma unroll
    for (int a = 0; a < AB; a++) {
        float4 q; q.x = mx[a][0]; q.y = mx[a][1]; q.z = mx[a][2]; q.w = mx[a][3];
        *(float4*)&pmaxp[(a * 8 + g) * H2 + ch2] = q;
    }
    __syncthreads();
    #pragma unroll
    for (int t = tid; t < AB * H2; t += 256) {
        const int a = t >> 7, ch = t & 127;
        float vv = pmaxp[(a * 8 + 0) * H2 + ch];
        #pragma unroll
        for (int gg = 1; gg < 8; gg++) vv = fmaxf(vv, pmaxp[(a * 8 + gg) * H2 + ch]);
        out[(size_t)(a0g + a) * H2 + ch] = vv;
    }
}

extern "C" void kernel_launch(void* const* d_in, const int* in_sizes, int n_in,
                              void* d_out, int out_size, void* d_ws, size_t ws_size,
                              hipStream_t stream) {
    const float* feat         = (const float*)d_in[0];
    const float* coord        = (const float*)d_in[1];
    const float* anchor_feat  = (const float*)d_in[2];
    const float* anchor_coord = (const float*)d_in[3];
    const float* W1  = (const float*)d_in[4];
    const float* b1  = (const float*)d_in[5];
    const float* g1  = (const float*)d_in[6];
    const float* be1 = (const float*)d_in[7];
    const float* W2  = (const float*)d_in[8];
    const float* b2  = (const float*)d_in[9];
    const float* g2  = (const float*)d_in[10];
    const float* be2 = (const float*)d_in[11];
    float* out = (float*)d_out;

    int*    maxn   = (int*)d_ws;                                  // 16 ints
    int*    idxbuf = (int*)d_ws + 16;                             // BB*MM*KNB ints
    float4* c4buf  = (float4*)((int*)d_ws + 16 + BB * MM * KNB);  // BB*NN float4 (16B aligned)

    init_kernel<<<1, 64, 0, stream>>>(maxn);
    coord4_kernel<<<(BB * NN + 255) / 256, 256, 0, stream>>>(coord, c4buf);
    knn_kernel<<<BB * MM / 2, 256, 0, stream>>>(c4buf, anchor_coord, idxbuf, maxn);
    mlp_kernel<<<BB * MM / AB, 256, 0, stream>>>(feat, coord, anchor_feat, anchor_coord,
                                                 W1, b1, g1, be1, W2, b2, g2, be2,
                                                 maxn, idxbuf, out);
}